// Round 1
// baseline (601.773 us; speedup 1.0000x reference)
//
#include <hip/hip_runtime.h>

typedef __attribute__((ext_vector_type(4))) float floatx4;
typedef __attribute__((ext_vector_type(8))) int   intx8;

// ---------------------------------------------------------------------------
// pack 4 floats (already clipped to +-448) into 4 e4m3 bytes, RNE
// ---------------------------------------------------------------------------
__device__ __forceinline__ unsigned int pack4_fp8(float f0, float f1, float f2, float f3) {
    int v = __builtin_amdgcn_cvt_pk_fp8_f32(f0, f1, 0, false);   // bytes 0,1
    v = __builtin_amdgcn_cvt_pk_fp8_f32(f2, f3, v, true);        // bytes 2,3
    return (unsigned int)v;
}

// async global->LDS, 16 B per lane. LDS dest must be wave-uniform;
// HW writes dest + lane*16. Global src is per-lane (pre-swizzled).
__device__ __forceinline__ void gload16(const unsigned char* g, unsigned char* l) {
    __builtin_amdgcn_global_load_lds(
        (const __attribute__((address_space(1))) unsigned int*)g,
        (__attribute__((address_space(3))) unsigned int*)l, 16, 0, 0);
}

// ---------------------------------------------------------------------------
// Kernel 0: classify the weight buffer's on-device dtype.
// fp8-exact values: as f32, low 20 mantissa bits are 0; as bf16, low nibble 0.
// flag: 0 = raw fp8 bytes, 1 = bf16-upcast, 2 = f32-upcast.
// ---------------------------------------------------------------------------
__global__ void detect_kernel(const unsigned int* __restrict__ W, int* __restrict__ flag) {
    __shared__ int ok[2];  // [f32ok, bf16ok]
    if (threadIdx.x == 0) { ok[0] = 1; ok[1] = 1; }
    __syncthreads();
    int f32ok = 1, bf16ok = 1;
#pragma unroll
    for (int i = 0; i < 16; ++i) {
        unsigned int w = W[threadIdx.x * 16 + i];   // first 16 KB of buffer
        if (w & 0x000FFFFFu) f32ok = 0;
        if (w & 0x000F000Fu) bf16ok = 0;
    }
    if (!f32ok)  atomicAnd(&ok[0], 0);
    if (!bf16ok) atomicAnd(&ok[1], 0);
    __syncthreads();
    if (threadIdx.x == 0) *flag = ok[0] ? 2 : (ok[1] ? 1 : 0);
}

// ---------------------------------------------------------------------------
// Kernel 1: quantize x (fp32) -> q (fp8 e4m3fn), q = clip(x/s, +-448)
// ---------------------------------------------------------------------------
__global__ void quant_kernel(const float* __restrict__ x,
                             unsigned int* __restrict__ q,
                             const float* __restrict__ iscale, int n8) {
    int i = blockIdx.x * blockDim.x + threadIdx.x;
    if (i >= n8) return;
    float s = iscale[0];
    const float4* xv = (const float4*)x;
    float4 a = xv[2 * i];
    float4 b = xv[2 * i + 1];
    float v[8] = {a.x, a.y, a.z, a.w, b.x, b.y, b.z, b.w};
#pragma unroll
    for (int j = 0; j < 8; ++j) {
        float t = v[j] / s;
        v[j] = fminf(fmaxf(t, -448.0f), 448.0f);
    }
    q[2 * i]     = pack4_fp8(v[0], v[1], v[2], v[3]);
    q[2 * i + 1] = pack4_fp8(v[4], v[5], v[6], v[7]);
}

// ---------------------------------------------------------------------------
// Kernel 2: ingest weight [K,N] (any of the 3 dtypes) -> Wt [N,K] fp8 bytes,
// via 64x64 LDS tile. Single launch; runtime uniform branch on *flag.
// ---------------------------------------------------------------------------
template <int MODE>
__device__ __forceinline__ void ingest_body(const unsigned char* __restrict__ W,
                                            unsigned char* __restrict__ Wt,
                                            int K, int N,
                                            unsigned char (*tile)[68]) {
    const int k0 = blockIdx.y * 64;
    const int n0 = blockIdx.x * 64;
    const int t = threadIdx.x;          // 256 threads
    const int kr = t >> 2;              // k-row within tile
    const int cg = (t & 3) * 16;        // n-column group (16 values)
    const size_t eidx = (size_t)(k0 + kr) * N + (n0 + cg);  // element index

    unsigned int w4[4];
    if constexpr (MODE == 0) {          // raw fp8 bytes
        uint4 v = *(const uint4*)(W + eidx);
        w4[0] = v.x; w4[1] = v.y; w4[2] = v.z; w4[3] = v.w;
    } else if constexpr (MODE == 1) {   // bf16-upcast (2 B/elem)
        const uint4* p = (const uint4*)((const unsigned short*)W + eidx);
        uint4 A0 = p[0], A1 = p[1];
        unsigned int uw[8] = {A0.x, A0.y, A0.z, A0.w, A1.x, A1.y, A1.z, A1.w};
#pragma unroll
        for (int g = 0; g < 4; ++g) {
            float f0 = __uint_as_float((uw[2 * g] & 0xFFFFu) << 16);
            float f1 = __uint_as_float((uw[2 * g] >> 16) << 16);
            float f2 = __uint_as_float((uw[2 * g + 1] & 0xFFFFu) << 16);
            float f3 = __uint_as_float((uw[2 * g + 1] >> 16) << 16);
            w4[g] = pack4_fp8(f0, f1, f2, f3);
        }
    } else {                            // f32-upcast (4 B/elem)
        const float4* p = (const float4*)((const float*)W + eidx);
#pragma unroll
        for (int g = 0; g < 4; ++g) {
            float4 f = p[g];
            w4[g] = pack4_fp8(f.x, f.y, f.z, f.w);
        }
    }
#pragma unroll
    for (int g = 0; g < 4; ++g)
        *(unsigned int*)&tile[kr][cg + 4 * g] = w4[g];   // 4B-aligned (68%4==0)
    __syncthreads();

    const int nr = t >> 2;
    const int kg = (t & 3) * 16;
    uint4 o;
    unsigned int w[4];
#pragma unroll
    for (int g = 0; g < 4; ++g) {
        unsigned int b0 = tile[kg + g * 4 + 0][nr];
        unsigned int b1 = tile[kg + g * 4 + 1][nr];
        unsigned int b2 = tile[kg + g * 4 + 2][nr];
        unsigned int b3 = tile[kg + g * 4 + 3][nr];
        w[g] = b0 | (b1 << 8) | (b2 << 16) | (b3 << 24);
    }
    o.x = w[0]; o.y = w[1]; o.z = w[2]; o.w = w[3];
    *(uint4*)(Wt + (size_t)(n0 + nr) * K + k0 + kg) = o;  // 16B-aligned
}

__global__ void ingest_kernel(const unsigned char* __restrict__ W,
                              unsigned char* __restrict__ Wt,
                              const int* __restrict__ flag, int K, int N) {
    __shared__ __align__(16) unsigned char tile[64][68];
    const int mode = *flag;             // global & uniform -> no divergence
    if (mode == 0)      ingest_body<0>(W, Wt, K, N, tile);
    else if (mode == 1) ingest_body<1>(W, Wt, K, N, tile);
    else                ingest_body<2>(W, Wt, K, N, tile);
}

// ---------------------------------------------------------------------------
// Kernel 3: MX-scaled fp8 GEMM (scales = 1.0). 128x128 tile, BK=128,
// mfma_scale_f32_16x16x128_f8f6f4 (2x the non-scaled fp8 rate, 4x K/instr).
//
// LDS layout (per 16 KB tile buffer): 8 row-blocks (rb) of 16 rows; each
// rb is two 1024 B lane-linear regions (rg=0,1). Slot (rb,rg,lane) holds the
// 16 global bytes  A[bm + rb*16 + (lane&15)][kt*128 + (lane>>4)*32 + rg*16].
// => fragment read for (rb): ds_read_b128 at rb*2048 + lane*16 (and +1024)
//    yields lane-contiguous 32 K-bytes: dense, bank-conflict-free; staging is
//    global_load_lds(16B) with the per-lane source pre-swizzled (LDS linear).
//
// Pipeline: double-buffered LDS, stage(next) issued BEFORE compute(cur),
// single __syncthreads() per K-tile (drain happens under the 16-MFMA phase).
// ---------------------------------------------------------------------------
__global__ __launch_bounds__(256, 2) void gemm_mxfp8_kernel(
    const unsigned char* __restrict__ A,   // [M,K] fp8
    const unsigned char* __restrict__ Bt,  // [N,K] fp8
    float* __restrict__ C,                 // [M,N] fp32
    const float* __restrict__ bias,        // [N]
    const float* __restrict__ wscale,
    const float* __restrict__ iscale,
    int M, int N, int K) {
    __shared__ __align__(16) unsigned char As[2][16384];
    __shared__ __align__(16) unsigned char Bs[2][16384];

    const int tid  = threadIdx.x;
    const int lane = tid & 63;
    const int wv   = tid >> 6;          // 4 waves
    const int wm   = wv >> 1;           // 2x2 wave grid, each owns 64x64
    const int wn   = wv & 1;
    const int r16  = lane & 15;
    const int cq   = lane >> 4;         // 0..3

    // T1: XCD-aware bijective block swizzle (nwg = 4096, divisible by 8)
    const int nbx  = gridDim.x;
    const int nwg  = nbx * gridDim.y;
    const int orig = blockIdx.y * nbx + blockIdx.x;
    const int cpx  = nwg >> 3;
    const int swz  = (orig & 7) * cpx + (orig >> 3);
    const int bm   = (swz / nbx) * 128;
    const int bn   = (swz % nbx) * 128;

    // staging: 16 x 1 KB units per operand tile; wave wv owns units wv*4+j
    const unsigned char* ga[4];
    const unsigned char* gb[4];
    int lo[4];
#pragma unroll
    for (int j = 0; j < 4; ++j) {
        const int u   = wv * 4 + j;     // 0..15
        const int rb  = u >> 1;
        const int rg  = u & 1;
        const int row = rb * 16 + r16;
        const int col = cq * 32 + rg * 16;   // per-lane pre-swizzled source
        ga[j] = A  + (size_t)(bm + row) * K + col;
        gb[j] = Bt + (size_t)(bn + row) * K + col;
        lo[j] = rb * 2048 + rg * 1024;       // wave-uniform LDS base
    }

    floatx4 acc[4][4] = {};

    // prologue: stage K-tile 0 into buffer 0
#pragma unroll
    for (int j = 0; j < 4; ++j) {
        gload16(ga[j], &As[0][lo[j]]);
        gload16(gb[j], &Bs[0][lo[j]]);
        ga[j] += 128; gb[j] += 128;
    }
    __syncthreads();                    // drains vmcnt -> buf0 ready

    const unsigned char* pa0 = &As[0][wm * 4 * 2048 + lane * 16];
    const unsigned char* pb0 = &Bs[0][wn * 4 * 2048 + lane * 16];

    union U8 { intx8 v; uint4 q[2]; };
    const int NT = K >> 7;              // K / 128
    int cur = 0;
    for (int kt = 0; kt < NT; ++kt) {
        if (kt + 1 < NT) {              // issue async prefetch of next tile
#pragma unroll
            for (int j = 0; j < 4; ++j) {
                gload16(ga[j], &As[cur ^ 1][lo[j]]);
                gload16(gb[j], &Bs[cur ^ 1][lo[j]]);
                ga[j] += 128; gb[j] += 128;
            }
        }
        intx8 af[4], bf[4];
#pragma unroll
        for (int i = 0; i < 4; ++i) {   // 16 x ds_read_b128, conflict-free
            U8 ua, ub;
            const unsigned char* qa = pa0 + cur * 16384 + i * 2048;
            const unsigned char* qb = pb0 + cur * 16384 + i * 2048;
            ua.q[0] = *(const uint4*)qa;
            ua.q[1] = *(const uint4*)(qa + 1024);
            ub.q[0] = *(const uint4*)qb;
            ub.q[1] = *(const uint4*)(qb + 1024);
            af[i] = ua.v;
            bf[i] = ub.v;
        }
#pragma unroll
        for (int im = 0; im < 4; ++im)
#pragma unroll
            for (int in = 0; in < 4; ++in)
                acc[im][in] = __builtin_amdgcn_mfma_scale_f32_16x16x128_f8f6f4(
                    af[im], bf[in], acc[im][in],
                    0, 0,                       // cbsz=fp8(e4m3), blgp=fp8
                    0, 0x7F7F7F7F,              // scale_a opsel, E8M0 1.0
                    0, 0x7F7F7F7F);             // scale_b opsel, E8M0 1.0
        __syncthreads();                // drain prefetch + protect buf reuse
        cur ^= 1;
    }
    (void)M;

    const float scale = iscale[0] * wscale[0];
    const int row0 = bm + wm * 64 + (cq << 2);   // C/D: col=lane&15, row=(lane>>4)*4+r
    const int col0 = bn + wn * 64 + r16;
#pragma unroll
    for (int in = 0; in < 4; ++in) {
        const int col = col0 + in * 16;
        const float bv = bias[col];
#pragma unroll
        for (int im = 0; im < 4; ++im) {
            const int row = row0 + im * 16;
            float* cp = C + (size_t)row * N + col;
#pragma unroll
            for (int r = 0; r < 4; ++r)
                cp[(size_t)r * N] = acc[im][in][r] * scale + bv;
        }
    }
}

extern "C" void kernel_launch(void* const* d_in, const int* in_sizes, int n_in,
                              void* d_out, int out_size, void* d_ws, size_t ws_size,
                              hipStream_t stream) {
    const float* x          = (const float*)d_in[0];
    const unsigned char* w  = (const unsigned char*)d_in[1];
    const float* wscale     = (const float*)d_in[2];
    const float* iscale     = (const float*)d_in[3];
    const float* bias       = (const float*)d_in[4];
    float* out              = (float*)d_out;

    const int D_OUT = in_sizes[4];            // 8192
    const int D_IN  = in_sizes[1] / D_OUT;    // 2048
    const int M     = in_sizes[0] / D_IN;     // 8192

    int* flag         = (int*)d_ws;
    unsigned char* q  = (unsigned char*)d_ws + 256;
    unsigned char* wt = q + (size_t)M * D_IN;

    detect_kernel<<<1, 256, 0, stream>>>((const unsigned int*)w, flag);
    const int n8 = (M * D_IN) / 8;
    quant_kernel<<<(n8 + 255) / 256, 256, 0, stream>>>(x, (unsigned int*)q, iscale, n8);
    dim3 tg(D_OUT / 64, D_IN / 64);
    ingest_kernel<<<tg, 256, 0, stream>>>(w, wt, flag, D_IN, D_OUT);
    gemm_mxfp8_kernel<<<dim3(D_OUT / 128, M / 128), 256, 0, stream>>>(
        q, wt, out, bias, wscale, iscale, M, D_OUT, D_IN);
}

// Round 2
// 570.979 us; speedup vs baseline: 1.0539x; 1.0539x over previous
//
#include <hip/hip_runtime.h>

typedef __attribute__((ext_vector_type(4))) float floatx4;
typedef __attribute__((ext_vector_type(8))) int   intx8;

// ---------------------------------------------------------------------------
// pack 4 floats (already clipped to +-448) into 4 e4m3 bytes, RNE
// ---------------------------------------------------------------------------
__device__ __forceinline__ unsigned int pack4_fp8(float f0, float f1, float f2, float f3) {
    int v = __builtin_amdgcn_cvt_pk_fp8_f32(f0, f1, 0, false);   // bytes 0,1
    v = __builtin_amdgcn_cvt_pk_fp8_f32(f2, f3, v, true);        // bytes 2,3
    return (unsigned int)v;
}

// async global->LDS, 16 B per lane. LDS dest is wave-uniform; HW writes
// dest + lane*16. Global src is per-lane (pre-swizzled to match).
__device__ __forceinline__ void gload16(const unsigned char* g, unsigned char* l) {
    __builtin_amdgcn_global_load_lds(
        (const __attribute__((address_space(1))) unsigned int*)g,
        (__attribute__((address_space(3))) unsigned int*)l, 16, 0, 0);
}

// ---------------------------------------------------------------------------
// Kernel 0: classify the weight buffer's on-device dtype.
// fp8-exact values: as f32, low 20 mantissa bits are 0; as bf16, low nibble 0.
// flag: 0 = raw fp8 bytes, 1 = bf16-upcast, 2 = f32-upcast.
// ---------------------------------------------------------------------------
__global__ void detect_kernel(const unsigned int* __restrict__ W, int* __restrict__ flag) {
    __shared__ int ok[2];  // [f32ok, bf16ok]
    if (threadIdx.x == 0) { ok[0] = 1; ok[1] = 1; }
    __syncthreads();
    int f32ok = 1, bf16ok = 1;
#pragma unroll
    for (int i = 0; i < 16; ++i) {
        unsigned int w = W[threadIdx.x * 16 + i];   // first 16 KB of buffer
        if (w & 0x000FFFFFu) f32ok = 0;
        if (w & 0x000F000Fu) bf16ok = 0;
    }
    if (!f32ok)  atomicAnd(&ok[0], 0);
    if (!bf16ok) atomicAnd(&ok[1], 0);
    __syncthreads();
    if (threadIdx.x == 0) *flag = ok[0] ? 2 : (ok[1] ? 1 : 0);
}

// ---------------------------------------------------------------------------
// Kernel 1: quantize x (fp32) -> q (fp8 e4m3fn), q = clip(x/s, +-448)
// ---------------------------------------------------------------------------
__global__ void quant_kernel(const float* __restrict__ x,
                             unsigned int* __restrict__ q,
                             const float* __restrict__ iscale, int n8) {
    int i = blockIdx.x * blockDim.x + threadIdx.x;
    if (i >= n8) return;
    float s = iscale[0];
    const float4* xv = (const float4*)x;
    float4 a = xv[2 * i];
    float4 b = xv[2 * i + 1];
    float v[8] = {a.x, a.y, a.z, a.w, b.x, b.y, b.z, b.w};
#pragma unroll
    for (int j = 0; j < 8; ++j) {
        float t = v[j] / s;
        v[j] = fminf(fmaxf(t, -448.0f), 448.0f);
    }
    q[2 * i]     = pack4_fp8(v[0], v[1], v[2], v[3]);
    q[2 * i + 1] = pack4_fp8(v[4], v[5], v[6], v[7]);
}

// ---------------------------------------------------------------------------
// Kernel 2: ingest weight [K,N] (any of the 3 dtypes) -> Wt [N,K] fp8 bytes,
// via 64x64 LDS tile. Single launch; runtime uniform branch on *flag.
// ---------------------------------------------------------------------------
template <int MODE>
__device__ __forceinline__ void ingest_body(const unsigned char* __restrict__ W,
                                            unsigned char* __restrict__ Wt,
                                            int K, int N,
                                            unsigned char (*tile)[68]) {
    const int k0 = blockIdx.y * 64;
    const int n0 = blockIdx.x * 64;
    const int t = threadIdx.x;          // 256 threads
    const int kr = t >> 2;              // k-row within tile
    const int cg = (t & 3) * 16;        // n-column group (16 values)
    const size_t eidx = (size_t)(k0 + kr) * N + (n0 + cg);  // element index

    unsigned int w4[4];
    if constexpr (MODE == 0) {          // raw fp8 bytes
        uint4 v = *(const uint4*)(W + eidx);
        w4[0] = v.x; w4[1] = v.y; w4[2] = v.z; w4[3] = v.w;
    } else if constexpr (MODE == 1) {   // bf16-upcast (2 B/elem)
        const uint4* p = (const uint4*)((const unsigned short*)W + eidx);
        uint4 A0 = p[0], A1 = p[1];
        unsigned int uw[8] = {A0.x, A0.y, A0.z, A0.w, A1.x, A1.y, A1.z, A1.w};
#pragma unroll
        for (int g = 0; g < 4; ++g) {
            float f0 = __uint_as_float((uw[2 * g] & 0xFFFFu) << 16);
            float f1 = __uint_as_float((uw[2 * g] >> 16) << 16);
            float f2 = __uint_as_float((uw[2 * g + 1] & 0xFFFFu) << 16);
            float f3 = __uint_as_float((uw[2 * g + 1] >> 16) << 16);
            w4[g] = pack4_fp8(f0, f1, f2, f3);
        }
    } else {                            // f32-upcast (4 B/elem)
        const float4* p = (const float4*)((const float*)W + eidx);
#pragma unroll
        for (int g = 0; g < 4; ++g) {
            float4 f = p[g];
            w4[g] = pack4_fp8(f.x, f.y, f.z, f.w);
        }
    }
#pragma unroll
    for (int g = 0; g < 4; ++g)
        *(unsigned int*)&tile[kr][cg + 4 * g] = w4[g];   // 4B-aligned (68%4==0)
    __syncthreads();

    const int nr = t >> 2;
    const int kg = (t & 3) * 16;
    uint4 o;
    unsigned int w[4];
#pragma unroll
    for (int g = 0; g < 4; ++g) {
        unsigned int b0 = tile[kg + g * 4 + 0][nr];
        unsigned int b1 = tile[kg + g * 4 + 1][nr];
        unsigned int b2 = tile[kg + g * 4 + 2][nr];
        unsigned int b3 = tile[kg + g * 4 + 3][nr];
        w[g] = b0 | (b1 << 8) | (b2 << 16) | (b3 << 24);
    }
    o.x = w[0]; o.y = w[1]; o.z = w[2]; o.w = w[3];
    *(uint4*)(Wt + (size_t)(n0 + nr) * K + k0 + kg) = o;  // 16B-aligned
}

__global__ void ingest_kernel(const unsigned char* __restrict__ W,
                              unsigned char* __restrict__ Wt,
                              const int* __restrict__ flag, int K, int N) {
    __shared__ __align__(16) unsigned char tile[64][68];
    const int mode = *flag;             // global & uniform -> no divergence
    if (mode == 0)      ingest_body<0>(W, Wt, K, N, tile);
    else if (mode == 1) ingest_body<1>(W, Wt, K, N, tile);
    else                ingest_body<2>(W, Wt, K, N, tile);
}

// ---------------------------------------------------------------------------
// Kernel 3: MX-scaled fp8 GEMM (scales = 1.0). 128x128 tile, BK=128,
// mfma_scale_f32_16x16x128_f8f6f4 (2x the non-scaled fp8 rate, 4x K/instr).
//
// ROUND-2 CHANGE (m97/m148 operating point): SINGLE-buffered 32 KB LDS so
// 4 blocks/CU fit (was dbuf 64 KB -> 2 blocks/CU, Occupancy 22%, everything-
// low latency-bound counters). Pipelining comes from implicit wave-level
// overlap across resident blocks (m114/m148: 1628 TF MX-fp8 on this exact
// structure), not from explicit dbuf. Also dropped the XCD swizzle: measured
// FETCH_SIZE 131 MB (linear) vs 533 MB (row-band swizzle) -> linear wins.
//
// LDS layout (per 16 KB operand tile): 8 row-blocks (rb) of 16 rows; each rb
// is two 1024 B lane-linear regions (rg). Slot (rb,rg,lane) holds the 16
// global bytes  A[bm + rb*16 + (lane&15)][kt*128 + (lane>>4)*32 + rg*16].
// Fragment read for rb: ds_read_b128 at rb*2048 + lane*16 (and +1024) ->
// lane-contiguous 32 K-bytes, dense, bank-conflict-free (measured 0).
// ---------------------------------------------------------------------------
__global__ __launch_bounds__(256, 4) void gemm_mxfp8_kernel(
    const unsigned char* __restrict__ A,   // [M,K] fp8
    const unsigned char* __restrict__ Bt,  // [N,K] fp8
    float* __restrict__ C,                 // [M,N] fp32
    const float* __restrict__ bias,        // [N]
    const float* __restrict__ wscale,
    const float* __restrict__ iscale,
    int M, int N, int K) {
    __shared__ __align__(16) unsigned char As[16384];
    __shared__ __align__(16) unsigned char Bs[16384];

    const int tid  = threadIdx.x;
    const int lane = tid & 63;
    const int wv   = tid >> 6;          // 4 waves
    const int wm   = wv >> 1;           // 2x2 wave grid, each owns 64x64
    const int wn   = wv & 1;
    const int r16  = lane & 15;
    const int cq   = lane >> 4;         // 0..3

    const int bm = blockIdx.y * 128;    // linear block order (no swizzle)
    const int bn = blockIdx.x * 128;

    // staging: 16 x 1 KB units per operand tile; wave wv owns units wv*4+j
    const unsigned char* ga[4];
    const unsigned char* gb[4];
    int lo[4];
#pragma unroll
    for (int j = 0; j < 4; ++j) {
        const int u   = wv * 4 + j;     // 0..15
        const int rb  = u >> 1;
        const int rg  = u & 1;
        const int row = rb * 16 + r16;
        const int col = cq * 32 + rg * 16;   // per-lane pre-swizzled source
        ga[j] = A  + (size_t)(bm + row) * K + col;
        gb[j] = Bt + (size_t)(bn + row) * K + col;
        lo[j] = rb * 2048 + rg * 1024;       // wave-uniform LDS base
    }

    floatx4 acc[4][4] = {};

    const unsigned char* pa0 = &As[wm * 4 * 2048 + lane * 16];
    const unsigned char* pb0 = &Bs[wn * 4 * 2048 + lane * 16];

    union U8 { intx8 v; uint4 q[2]; };
    const int NT = K >> 7;              // K / 128
    for (int kt = 0; kt < NT; ++kt) {
        __syncthreads();                // prev tile's ds_reads complete
#pragma unroll
        for (int j = 0; j < 4; ++j) {   // stage tile kt (async, 16B DMA)
            gload16(ga[j], &As[lo[j]]);
            gload16(gb[j], &Bs[lo[j]]);
            ga[j] += 128; gb[j] += 128;
        }
        __syncthreads();                // vmcnt drain -> tile ready

        intx8 af[4], bf[4];
#pragma unroll
        for (int i = 0; i < 4; ++i) {   // 16 x ds_read_b128, conflict-free
            U8 ua, ub;
            const unsigned char* qa = pa0 + i * 2048;
            const unsigned char* qb = pb0 + i * 2048;
            ua.q[0] = *(const uint4*)qa;
            ua.q[1] = *(const uint4*)(qa + 1024);
            ub.q[0] = *(const uint4*)qb;
            ub.q[1] = *(const uint4*)(qb + 1024);
            af[i] = ua.v;
            bf[i] = ub.v;
        }
#pragma unroll
        for (int im = 0; im < 4; ++im)
#pragma unroll
            for (int in = 0; in < 4; ++in)
                acc[im][in] = __builtin_amdgcn_mfma_scale_f32_16x16x128_f8f6f4(
                    af[im], bf[in], acc[im][in],
                    0, 0,                       // cbsz=fp8(e4m3), blgp=fp8
                    0, 0x7F7F7F7F,              // scale_a opsel, E8M0 1.0
                    0, 0x7F7F7F7F);             // scale_b opsel, E8M0 1.0
    }
    (void)M;

    const float scale = iscale[0] * wscale[0];
    const int row0 = bm + wm * 64 + (cq << 2);   // C/D: col=lane&15, row=(lane>>4)*4+r
    const int col0 = bn + wn * 64 + r16;
#pragma unroll
    for (int in = 0; in < 4; ++in) {
        const int col = col0 + in * 16;
        const float bv = bias[col];
#pragma unroll
        for (int im = 0; im < 4; ++im) {
            const int row = row0 + im * 16;
            float* cp = C + (size_t)row * N + col;
#pragma unroll
            for (int r = 0; r < 4; ++r)
                cp[(size_t)r * N] = acc[im][in][r] * scale + bv;
        }
    }
}

extern "C" void kernel_launch(void* const* d_in, const int* in_sizes, int n_in,
                              void* d_out, int out_size, void* d_ws, size_t ws_size,
                              hipStream_t stream) {
    const float* x          = (const float*)d_in[0];
    const unsigned char* w  = (const unsigned char*)d_in[1];
    const float* wscale     = (const float*)d_in[2];
    const float* iscale     = (const float*)d_in[3];
    const float* bias       = (const float*)d_in[4];
    float* out              = (float*)d_out;

    const int D_OUT = in_sizes[4];            // 8192
    const int D_IN  = in_sizes[1] / D_OUT;    // 2048
    const int M     = in_sizes[0] / D_IN;     // 8192

    int* flag         = (int*)d_ws;
    unsigned char* q  = (unsigned char*)d_ws + 256;
    unsigned char* wt = q + (size_t)M * D_IN;

    detect_kernel<<<1, 256, 0, stream>>>((const unsigned int*)w, flag);
    const int n8 = (M * D_IN) / 8;
    quant_kernel<<<(n8 + 255) / 256, 256, 0, stream>>>(x, (unsigned int*)q, iscale, n8);
    dim3 tg(D_OUT / 64, D_IN / 64);
    ingest_kernel<<<tg, 256, 0, stream>>>(w, wt, flag, D_IN, D_OUT);
    gemm_mxfp8_kernel<<<dim3(D_OUT / 128, M / 128), 256, 0, stream>>>(
        q, wt, out, bias, wscale, iscale, M, D_OUT, D_IN);
}

// Round 3
// 561.187 us; speedup vs baseline: 1.0723x; 1.0174x over previous
//
#include <hip/hip_runtime.h>

typedef __attribute__((ext_vector_type(4))) float floatx4;
typedef __attribute__((ext_vector_type(8))) int   intx8;

// ---------------------------------------------------------------------------
// pack 4 floats (already clipped to +-448) into 4 e4m3 bytes, RNE
// ---------------------------------------------------------------------------
__device__ __forceinline__ unsigned int pack4_fp8(float f0, float f1, float f2, float f3) {
    int v = __builtin_amdgcn_cvt_pk_fp8_f32(f0, f1, 0, false);   // bytes 0,1
    v = __builtin_amdgcn_cvt_pk_fp8_f32(f2, f3, v, true);        // bytes 2,3
    return (unsigned int)v;
}

// async global->LDS, 16 B per lane. LDS dest is wave-uniform; HW writes
// dest + lane*16. Global src is per-lane (pre-swizzled to match).
__device__ __forceinline__ void gload16(const unsigned char* g, unsigned char* l) {
    __builtin_amdgcn_global_load_lds(
        (const __attribute__((address_space(1))) unsigned int*)g,
        (__attribute__((address_space(3))) unsigned int*)l, 16, 0, 0);
}

// ---------------------------------------------------------------------------
// Kernel 0: classify the weight buffer's on-device dtype.
// flag: 0 = raw fp8 bytes, 1 = bf16-upcast, 2 = f32-upcast.
// ---------------------------------------------------------------------------
__global__ void detect_kernel(const unsigned int* __restrict__ W, int* __restrict__ flag) {
    __shared__ int ok[2];  // [f32ok, bf16ok]
    if (threadIdx.x == 0) { ok[0] = 1; ok[1] = 1; }
    __syncthreads();
    int f32ok = 1, bf16ok = 1;
#pragma unroll
    for (int i = 0; i < 16; ++i) {
        unsigned int w = W[threadIdx.x * 16 + i];   // first 16 KB of buffer
        if (w & 0x000FFFFFu) f32ok = 0;
        if (w & 0x000F000Fu) bf16ok = 0;
    }
    if (!f32ok)  atomicAnd(&ok[0], 0);
    if (!bf16ok) atomicAnd(&ok[1], 0);
    __syncthreads();
    if (threadIdx.x == 0) *flag = ok[0] ? 2 : (ok[1] ? 1 : 0);
}

// ---------------------------------------------------------------------------
// Kernel 1: quantize x (fp32) -> q (fp8 e4m3fn), q = clip(x/s, +-448)
// ---------------------------------------------------------------------------
__global__ void quant_kernel(const float* __restrict__ x,
                             unsigned int* __restrict__ q,
                             const float* __restrict__ iscale, int n8) {
    int i = blockIdx.x * blockDim.x + threadIdx.x;
    if (i >= n8) return;
    float s = iscale[0];
    const float4* xv = (const float4*)x;
    float4 a = xv[2 * i];
    float4 b = xv[2 * i + 1];
    float v[8] = {a.x, a.y, a.z, a.w, b.x, b.y, b.z, b.w};
#pragma unroll
    for (int j = 0; j < 8; ++j) {
        float t = v[j] / s;
        v[j] = fminf(fmaxf(t, -448.0f), 448.0f);
    }
    q[2 * i]     = pack4_fp8(v[0], v[1], v[2], v[3]);
    q[2 * i + 1] = pack4_fp8(v[4], v[5], v[6], v[7]);
}

// ---------------------------------------------------------------------------
// Kernel 2: ingest weight [K,N] (any of the 3 dtypes) -> Wt [N,K] fp8 bytes,
// via 64x64 LDS tile. Single launch; runtime uniform branch on *flag.
// ---------------------------------------------------------------------------
template <int MODE>
__device__ __forceinline__ void ingest_body(const unsigned char* __restrict__ W,
                                            unsigned char* __restrict__ Wt,
                                            int K, int N,
                                            unsigned char (*tile)[68]) {
    const int k0 = blockIdx.y * 64;
    const int n0 = blockIdx.x * 64;
    const int t = threadIdx.x;          // 256 threads
    const int kr = t >> 2;              // k-row within tile
    const int cg = (t & 3) * 16;        // n-column group (16 values)
    const size_t eidx = (size_t)(k0 + kr) * N + (n0 + cg);  // element index

    unsigned int w4[4];
    if constexpr (MODE == 0) {          // raw fp8 bytes
        uint4 v = *(const uint4*)(W + eidx);
        w4[0] = v.x; w4[1] = v.y; w4[2] = v.z; w4[3] = v.w;
    } else if constexpr (MODE == 1) {   // bf16-upcast (2 B/elem)
        const uint4* p = (const uint4*)((const unsigned short*)W + eidx);
        uint4 A0 = p[0], A1 = p[1];
        unsigned int uw[8] = {A0.x, A0.y, A0.z, A0.w, A1.x, A1.y, A1.z, A1.w};
#pragma unroll
        for (int g = 0; g < 4; ++g) {
            float f0 = __uint_as_float((uw[2 * g] & 0xFFFFu) << 16);
            float f1 = __uint_as_float((uw[2 * g] >> 16) << 16);
            float f2 = __uint_as_float((uw[2 * g + 1] & 0xFFFFu) << 16);
            float f3 = __uint_as_float((uw[2 * g + 1] >> 16) << 16);
            w4[g] = pack4_fp8(f0, f1, f2, f3);
        }
    } else {                            // f32-upcast (4 B/elem)
        const float4* p = (const float4*)((const float*)W + eidx);
#pragma unroll
        for (int g = 0; g < 4; ++g) {
            float4 f = p[g];
            w4[g] = pack4_fp8(f.x, f.y, f.z, f.w);
        }
    }
#pragma unroll
    for (int g = 0; g < 4; ++g)
        *(unsigned int*)&tile[kr][cg + 4 * g] = w4[g];   // 4B-aligned (68%4==0)
    __syncthreads();

    const int nr = t >> 2;
    const int kg = (t & 3) * 16;
    uint4 o;
    unsigned int w[4];
#pragma unroll
    for (int g = 0; g < 4; ++g) {
        unsigned int b0 = tile[kg + g * 4 + 0][nr];
        unsigned int b1 = tile[kg + g * 4 + 1][nr];
        unsigned int b2 = tile[kg + g * 4 + 2][nr];
        unsigned int b3 = tile[kg + g * 4 + 3][nr];
        w[g] = b0 | (b1 << 8) | (b2 << 16) | (b3 << 24);
    }
    o.x = w[0]; o.y = w[1]; o.z = w[2]; o.w = w[3];
    *(uint4*)(Wt + (size_t)(n0 + nr) * K + k0 + kg) = o;  // 16B-aligned
}

__global__ void ingest_kernel(const unsigned char* __restrict__ W,
                              unsigned char* __restrict__ Wt,
                              const int* __restrict__ flag, int K, int N) {
    __shared__ __align__(16) unsigned char tile[64][68];
    const int mode = *flag;             // global & uniform -> no divergence
    if (mode == 0)      ingest_body<0>(W, Wt, K, N, tile);
    else if (mode == 1) ingest_body<1>(W, Wt, K, N, tile);
    else                ingest_body<2>(W, Wt, K, N, tile);
}

// ---------------------------------------------------------------------------
// Kernel 3: MX-scaled fp8 GEMM (scales = 1.0), 256x256 tile, BK=128,
// 8 waves (2M x 4N), 4-phase-per-K-tile schedule -- the m201 8-phase template
// ported to mfma_scale_f32_16x16x128_f8f6f4.
//
// ROUND-3 CHANGE: rounds 1-2 proved the 2-barrier/full-drain structure is the
// limiter (MfmaUtil pinned ~20% at both 22% and 42% occupancy). This is the
// regime-gated fix (T3+T4): raw s_barrier (no per-phase vmcnt drain), staging
// for tile t+1 issued in phases 0-1 of tile t (>=2 phases latency cover),
// vmcnt(0) exactly once per K-tile at the boundary. setprio(1) around MFMA
// clusters (T5 pays only on phase-split schedules).
//
// LDS (per 32 KB operand tile): 32 units of 1 KB, unit u = rb*2 + rg holds
// rows rb*16+(lane&15), K-bytes (lane>>4)*32 + rg*16 .. +15. Fragment for
// m-block g = two ds_read_b128 at g*2048 + lane*16 (+1024): lane-contiguous
// 32 K-bytes, dense, conflict-free (measured 0 in rounds 1-2). Verified
// 16x16x128 f8f6f4 fragment layout from rounds 1-2 kept unchanged.
//
// Hazards (sync-structure edit -> audited): buf c^1 DMA-written during tile t
// only after every wave's reads of it (tile t-1) completed before its P3
// lgkm-wait + boundary barrier; reads of tile t+1 gated by per-wave vmcnt(0)
// + boundary barrier; asm "memory" clobber + sched_barrier(0) stop hoisting.
// ---------------------------------------------------------------------------
__global__ __launch_bounds__(512, 2) void gemm_mxfp8_kernel(
    const unsigned char* __restrict__ A,   // [M,K] fp8
    const unsigned char* __restrict__ Bt,  // [N,K] fp8
    float* __restrict__ C,                 // [M,N] fp32
    const float* __restrict__ bias,        // [N]
    const float* __restrict__ wscale,
    const float* __restrict__ iscale,
    int M, int N, int K) {
    __shared__ __align__(16) unsigned char As[2][32768];
    __shared__ __align__(16) unsigned char Bs[2][32768];

    const int tid  = threadIdx.x;
    const int lane = tid & 63;
    const int wv   = tid >> 6;          // 8 waves
    const int wm   = wv >> 2;           // 2 (M) x 4 (N) wave grid
    const int wn   = wv & 3;
    const int r16  = lane & 15;
    const int cq   = lane >> 4;         // 0..3

    const int bm = blockIdx.y * 256;    // linear block order (round-2 measured)
    const int bn = blockIdx.x * 256;

    // staging: 32 x 1 KB units per operand tile; wave wv owns units wv*4+j
    const unsigned char* ga[4];
    const unsigned char* gb[4];
    int lo[4];
#pragma unroll
    for (int j = 0; j < 4; ++j) {
        const int u   = wv * 4 + j;     // 0..31
        const int rb  = u >> 1;
        const int rg  = u & 1;
        const int row = rb * 16 + r16;
        const int col = cq * 32 + rg * 16;   // per-lane pre-swizzled source
        ga[j] = A  + (size_t)(bm + row) * K + col;
        gb[j] = Bt + (size_t)(bn + row) * K + col;
        lo[j] = u * 1024;                    // wave-uniform LDS offset
    }

    floatx4 acc[8][4] = {};

    // prologue: stage K-tile 0 into buffer 0, full drain once
#pragma unroll
    for (int j = 0; j < 4; ++j) {
        gload16(ga[j], &As[0][lo[j]]);
        gload16(gb[j], &Bs[0][lo[j]]);
        ga[j] += 128; gb[j] += 128;
    }
    asm volatile("s_waitcnt vmcnt(0)" ::: "memory");
    __builtin_amdgcn_s_barrier();

    union U8 { intx8 v; uint4 q[2]; };
    const int NT = K >> 7;              // K / 128

#define READ_FRAG(dst, base, blk)                                   \
    do {                                                            \
        U8 _u;                                                      \
        const unsigned char* _p = (base) + (blk) * 2048 + lane * 16;\
        _u.q[0] = *(const uint4*)_p;                                \
        _u.q[1] = *(const uint4*)(_p + 1024);                       \
        (dst) = _u.v;                                               \
    } while (0)

#define MFMA8(a0, a1, i0, i1)                                               \
    do {                                                                    \
        __builtin_amdgcn_s_setprio(1);                                      \
        _Pragma("unroll")                                                   \
        for (int j = 0; j < 4; ++j)                                         \
            acc[i0][j] = __builtin_amdgcn_mfma_scale_f32_16x16x128_f8f6f4(  \
                a0, bf[j], acc[i0][j], 0, 0, 0, 0x7F7F7F7F, 0, 0x7F7F7F7F); \
        _Pragma("unroll")                                                   \
        for (int j = 0; j < 4; ++j)                                         \
            acc[i1][j] = __builtin_amdgcn_mfma_scale_f32_16x16x128_f8f6f4(  \
                a1, bf[j], acc[i1][j], 0, 0, 0, 0x7F7F7F7F, 0, 0x7F7F7F7F); \
        __builtin_amdgcn_s_setprio(0);                                      \
    } while (0)

#define PHASE_WAIT()                                             \
    do {                                                         \
        __builtin_amdgcn_s_barrier();                            \
        asm volatile("s_waitcnt lgkmcnt(0)" ::: "memory");       \
        __builtin_amdgcn_sched_barrier(0);                       \
    } while (0)

    for (int kt = 0; kt < NT; ++kt) {
        const unsigned char* Ab = As[kt & 1];
        const unsigned char* Bb = Bs[kt & 1];
        unsigned char* An = As[(kt & 1) ^ 1];
        unsigned char* Bn = Bs[(kt & 1) ^ 1];
        const bool pf = (kt + 1 < NT);

        intx8 bf[4], afa, afb;
        // ---- phase 0: all B frags + A frags 0,1; stage half of tile t+1
        READ_FRAG(bf[0], Bb, wn * 4 + 0);
        READ_FRAG(bf[1], Bb, wn * 4 + 1);
        READ_FRAG(bf[2], Bb, wn * 4 + 2);
        READ_FRAG(bf[3], Bb, wn * 4 + 3);
        READ_FRAG(afa, Ab, wm * 8 + 0);
        READ_FRAG(afb, Ab, wm * 8 + 1);
        if (pf) {
            gload16(ga[0], An + lo[0]); gload16(ga[1], An + lo[1]);
            gload16(gb[0], Bn + lo[0]); gload16(gb[1], Bn + lo[1]);
            ga[0] += 128; ga[1] += 128; gb[0] += 128; gb[1] += 128;
        }
        PHASE_WAIT();
        MFMA8(afa, afb, 0, 1);
        __builtin_amdgcn_s_barrier();

        // ---- phase 1: A frags 2,3; stage other half of tile t+1
        READ_FRAG(afa, Ab, wm * 8 + 2);
        READ_FRAG(afb, Ab, wm * 8 + 3);
        if (pf) {
            gload16(ga[2], An + lo[2]); gload16(ga[3], An + lo[3]);
            gload16(gb[2], Bn + lo[2]); gload16(gb[3], Bn + lo[3]);
            ga[2] += 128; ga[3] += 128; gb[2] += 128; gb[3] += 128;
        }
        PHASE_WAIT();
        MFMA8(afa, afb, 2, 3);
        __builtin_amdgcn_s_barrier();

        // ---- phase 2: A frags 4,5
        READ_FRAG(afa, Ab, wm * 8 + 4);
        READ_FRAG(afb, Ab, wm * 8 + 5);
        PHASE_WAIT();
        MFMA8(afa, afb, 4, 5);
        __builtin_amdgcn_s_barrier();

        // ---- phase 3: A frags 6,7; per-wave vmcnt drain ONCE per K-tile
        READ_FRAG(afa, Ab, wm * 8 + 6);
        READ_FRAG(afb, Ab, wm * 8 + 7);
        PHASE_WAIT();
        MFMA8(afa, afb, 6, 7);
        asm volatile("s_waitcnt vmcnt(0)" ::: "memory");  // tile t+1 landed
        __builtin_amdgcn_s_barrier();                     // release reads
    }
    (void)M;
#undef READ_FRAG
#undef MFMA8
#undef PHASE_WAIT

    const float scale = iscale[0] * wscale[0];
    const int row0 = bm + wm * 128 + (cq << 2);  // C/D: col=lane&15, row=cq*4+r
    const int col0 = bn + wn * 64 + r16;
#pragma unroll
    for (int j = 0; j < 4; ++j) {
        const int col = col0 + j * 16;
        const float bv = bias[col];
#pragma unroll
        for (int i = 0; i < 8; ++i) {
            const int row = row0 + i * 16;
            float* cp = C + (size_t)row * N + col;
#pragma unroll
            for (int r = 0; r < 4; ++r)
                cp[(size_t)r * N] = acc[i][j][r] * scale + bv;
        }
    }
}

extern "C" void kernel_launch(void* const* d_in, const int* in_sizes, int n_in,
                              void* d_out, int out_size, void* d_ws, size_t ws_size,
                              hipStream_t stream) {
    const float* x          = (const float*)d_in[0];
    const unsigned char* w  = (const unsigned char*)d_in[1];
    const float* wscale     = (const float*)d_in[2];
    const float* iscale     = (const float*)d_in[3];
    const float* bias       = (const float*)d_in[4];
    float* out              = (float*)d_out;

    const int D_OUT = in_sizes[4];            // 8192
    const int D_IN  = in_sizes[1] / D_OUT;    // 2048
    const int M     = in_sizes[0] / D_IN;     // 8192

    int* flag         = (int*)d_ws;
    unsigned char* q  = (unsigned char*)d_ws + 256;
    unsigned char* wt = q + (size_t)M * D_IN;

    detect_kernel<<<1, 256, 0, stream>>>((const unsigned int*)w, flag);
    const int n8 = (M * D_IN) / 8;
    quant_kernel<<<(n8 + 255) / 256, 256, 0, stream>>>(x, (unsigned int*)q, iscale, n8);
    dim3 tg(D_OUT / 64, D_IN / 64);
    ingest_kernel<<<tg, 256, 0, stream>>>(w, wt, flag, D_IN, D_OUT);
    gemm_mxfp8_kernel<<<dim3(D_OUT / 256, M / 256), 512, 0, stream>>>(
        q, wt, out, bias, wscale, iscale, M, D_OUT, D_IN);
}

// Round 5
// 549.817 us; speedup vs baseline: 1.0945x; 1.0207x over previous
//
#include <hip/hip_runtime.h>

typedef __attribute__((ext_vector_type(4))) float floatx4;
typedef __attribute__((ext_vector_type(8))) int   intx8;

// ---------------------------------------------------------------------------
// pack 4 floats (already clipped to +-448) into 4 e4m3 bytes, RNE
// ---------------------------------------------------------------------------
__device__ __forceinline__ unsigned int pack4_fp8(float f0, float f1, float f2, float f3) {
    int v = __builtin_amdgcn_cvt_pk_fp8_f32(f0, f1, 0, false);   // bytes 0,1
    v = __builtin_amdgcn_cvt_pk_fp8_f32(f2, f3, v, true);        // bytes 2,3
    return (unsigned int)v;
}

// async global->LDS, 16 B per lane. LDS dest is wave-uniform; HW writes
// dest + lane*16. Global src is per-lane (pre-swizzled to match).
__device__ __forceinline__ void gload16(const unsigned char* g, unsigned char* l) {
    __builtin_amdgcn_global_load_lds(
        (const __attribute__((address_space(1))) unsigned int*)g,
        (__attribute__((address_space(3))) unsigned int*)l, 16, 0, 0);
}

// ---------------------------------------------------------------------------
// Kernel 0: classify the weight buffer's on-device dtype.
// flag: 0 = raw fp8 bytes, 1 = bf16-upcast, 2 = f32-upcast.
// ---------------------------------------------------------------------------
__global__ void detect_kernel(const unsigned int* __restrict__ W, int* __restrict__ flag) {
    __shared__ int ok[2];  // [f32ok, bf16ok]
    if (threadIdx.x == 0) { ok[0] = 1; ok[1] = 1; }
    __syncthreads();
    int f32ok = 1, bf16ok = 1;
#pragma unroll
    for (int i = 0; i < 16; ++i) {
        unsigned int w = W[threadIdx.x * 16 + i];   // first 16 KB of buffer
        if (w & 0x000FFFFFu) f32ok = 0;
        if (w & 0x000F000Fu) bf16ok = 0;
    }
    if (!f32ok)  atomicAnd(&ok[0], 0);
    if (!bf16ok) atomicAnd(&ok[1], 0);
    __syncthreads();
    if (threadIdx.x == 0) *flag = ok[0] ? 2 : (ok[1] ? 1 : 0);
}

// ---------------------------------------------------------------------------
// Kernel 1: quantize x (fp32) -> q (fp8 e4m3fn), q = clip(x/s, +-448)
// ---------------------------------------------------------------------------
__global__ void quant_kernel(const float* __restrict__ x,
                             unsigned int* __restrict__ q,
                             const float* __restrict__ iscale, int n8) {
    int i = blockIdx.x * blockDim.x + threadIdx.x;
    if (i >= n8) return;
    float s = iscale[0];
    const float4* xv = (const float4*)x;
    float4 a = xv[2 * i];
    float4 b = xv[2 * i + 1];
    float v[8] = {a.x, a.y, a.z, a.w, b.x, b.y, b.z, b.w};
#pragma unroll
    for (int j = 0; j < 8; ++j) {
        float t = v[j] / s;
        v[j] = fminf(fmaxf(t, -448.0f), 448.0f);
    }
    q[2 * i]     = pack4_fp8(v[0], v[1], v[2], v[3]);
    q[2 * i + 1] = pack4_fp8(v[4], v[5], v[6], v[7]);
}

// ---------------------------------------------------------------------------
// Kernel 2: ingest weight [K,N] (any of the 3 dtypes) -> Wt [N,K] fp8 bytes,
// via 64x64 LDS tile. Single launch; runtime uniform branch on *flag.
// ---------------------------------------------------------------------------
template <int MODE>
__device__ __forceinline__ void ingest_body(const unsigned char* __restrict__ W,
                                            unsigned char* __restrict__ Wt,
                                            int K, int N,
                                            unsigned char (*tile)[68]) {
    const int k0 = blockIdx.y * 64;
    const int n0 = blockIdx.x * 64;
    const int t = threadIdx.x;          // 256 threads
    const int kr = t >> 2;              // k-row within tile
    const int cg = (t & 3) * 16;        // n-column group (16 values)
    const size_t eidx = (size_t)(k0 + kr) * N + (n0 + cg);  // element index

    unsigned int w4[4];
    if constexpr (MODE == 0) {          // raw fp8 bytes
        uint4 v = *(const uint4*)(W + eidx);
        w4[0] = v.x; w4[1] = v.y; w4[2] = v.z; w4[3] = v.w;
    } else if constexpr (MODE == 1) {   // bf16-upcast (2 B/elem)
        const uint4* p = (const uint4*)((const unsigned short*)W + eidx);
        uint4 A0 = p[0], A1 = p[1];
        unsigned int uw[8] = {A0.x, A0.y, A0.z, A0.w, A1.x, A1.y, A1.z, A1.w};
#pragma unroll
        for (int g = 0; g < 4; ++g) {
            float f0 = __uint_as_float((uw[2 * g] & 0xFFFFu) << 16);
            float f1 = __uint_as_float((uw[2 * g] >> 16) << 16);
            float f2 = __uint_as_float((uw[2 * g + 1] & 0xFFFFu) << 16);
            float f3 = __uint_as_float((uw[2 * g + 1] >> 16) << 16);
            w4[g] = pack4_fp8(f0, f1, f2, f3);
        }
    } else {                            // f32-upcast (4 B/elem)
        const float4* p = (const float4*)((const float*)W + eidx);
#pragma unroll
        for (int g = 0; g < 4; ++g) {
            float4 f = p[g];
            w4[g] = pack4_fp8(f.x, f.y, f.z, f.w);
        }
    }
#pragma unroll
    for (int g = 0; g < 4; ++g)
        *(unsigned int*)&tile[kr][cg + 4 * g] = w4[g];   // 4B-aligned (68%4==0)
    __syncthreads();

    const int nr = t >> 2;
    const int kg = (t & 3) * 16;
    uint4 o;
    unsigned int w[4];
#pragma unroll
    for (int g = 0; g < 4; ++g) {
        unsigned int b0 = tile[kg + g * 4 + 0][nr];
        unsigned int b1 = tile[kg + g * 4 + 1][nr];
        unsigned int b2 = tile[kg + g * 4 + 2][nr];
        unsigned int b3 = tile[kg + g * 4 + 3][nr];
        w[g] = b0 | (b1 << 8) | (b2 << 16) | (b3 << 24);
    }
    o.x = w[0]; o.y = w[1]; o.z = w[2]; o.w = w[3];
    *(uint4*)(Wt + (size_t)(n0 + nr) * K + k0 + kg) = o;  // 16B-aligned
}

__global__ void ingest_kernel(const unsigned char* __restrict__ W,
                              unsigned char* __restrict__ Wt,
                              const int* __restrict__ flag, int K, int N) {
    __shared__ __align__(16) unsigned char tile[64][68];
    const int mode = *flag;             // global & uniform -> no divergence
    if (mode == 0)      ingest_body<0>(W, Wt, K, N, tile);
    else if (mode == 1) ingest_body<1>(W, Wt, K, N, tile);
    else                ingest_body<2>(W, Wt, K, N, tile);
}

// ---------------------------------------------------------------------------
// Kernel 3: MX-scaled fp8 GEMM (scales = 1.0), 256x256 tile, BK=128,
// 8 waves (2M x 4N), 4 phases per K-tile.
//
// ROUND-5: identical to round 4 (bench infra failed; kernel audited clean).
// T4 counted-vmcnt schedule (m218: "T3's gain IS T4; drain0 == 1-phase"):
// rolling DMA with 2 buffers:
//   P0(t): A(t+1)[0,1]   P1(t): A(t+1)[2,3]     -> As[(t+1)&1]
//   P2(t): B(t+2)[0,1]   P3(t): B(t+2)[2,3]     -> Bs[t&1]  (B frags of tile
//                                                  t are only ds_read in P0)
// FIFO vmcnt accounting => boundary wait = vmcnt(4) (newest 4 = B(t+2) stay
// in flight). NEVER 0 in steady state. Prologue stages A(0)+B(0)+B(1), waits
// vmcnt(4). Tail (kt+2>=NT): vmcnt(0).
//
// Hazards: B(t+2) writes Bs[t&1] only after P1's closing barrier; all B-reads
// of tile t completed before P0(t)'s closing barrier (each wave's lgkmcnt(0)
// precedes its P0 MFMA precedes that barrier). A(t+1) writes As[(t+1)&1],
// whose last readers finished in tile t-1 (phase-p A-reads drained at p's
// lgkm wait). asm "memory" clobbers order all LDS ops across the waits.
// All barriers block-uniform (pfA/pfB/NT uniform) -> no divergent-barrier
// deadlock; vmcnt FIFO walk verified for NT in {1,2,16}.
//
// LDS layout & 16x16x128 f8f6f4 fragment mapping: verified rounds 1-3
// (0 bank conflicts, correctness passed).
// ---------------------------------------------------------------------------
__global__ __launch_bounds__(512, 2) void gemm_mxfp8_kernel(
    const unsigned char* __restrict__ A,   // [M,K] fp8
    const unsigned char* __restrict__ Bt,  // [N,K] fp8
    float* __restrict__ C,                 // [M,N] fp32
    const float* __restrict__ bias,        // [N]
    const float* __restrict__ wscale,
    const float* __restrict__ iscale,
    int M, int N, int K) {
    __shared__ __align__(16) unsigned char As[2 * 32768];
    __shared__ __align__(16) unsigned char Bs[2 * 32768];

    const int tid  = threadIdx.x;
    const int lane = tid & 63;
    const int wv   = tid >> 6;          // 8 waves
    const int wm   = wv >> 2;           // 2 (M) x 4 (N) wave grid
    const int wn   = wv & 3;
    const int r16  = lane & 15;
    const int cq   = lane >> 4;         // 0..3

    const int bm = blockIdx.y * 256;    // linear block order (round-2 measured)
    const int bn = blockIdx.x * 256;

    // staging: 32 x 1 KB units per operand tile; wave wv owns units wv*4+j
    const unsigned char* ga[4];
    const unsigned char* gb[4];
    int lo[4];
#pragma unroll
    for (int j = 0; j < 4; ++j) {
        const int u   = wv * 4 + j;     // 0..31
        const int rb  = u >> 1;
        const int rg  = u & 1;
        const int row = rb * 16 + r16;
        const int col = cq * 32 + rg * 16;   // per-lane pre-swizzled source
        ga[j] = A  + (size_t)(bm + row) * K + col;
        gb[j] = Bt + (size_t)(bn + row) * K + col;
        lo[j] = u * 1024;                    // wave-uniform LDS offset
    }

    floatx4 acc[8][4] = {};
    const int NT = K >> 7;              // K / 128

    // prologue: A(0)+B(0) -> buf0, B(1) -> buf1, wait all but newest 4
#pragma unroll
    for (int j = 0; j < 4; ++j) {
        gload16(ga[j], &As[lo[j]]);
        gload16(gb[j], &Bs[lo[j]]);
        ga[j] += 128; gb[j] += 128;
    }
    if (NT > 1) {
#pragma unroll
        for (int j = 0; j < 4; ++j) {
            gload16(gb[j], &Bs[32768 + lo[j]]);   // B(1) -> buf1
            gb[j] += 128;                         // gb now points at tile 2
        }
        asm volatile("s_waitcnt vmcnt(4)" ::: "memory");
    } else {
        asm volatile("s_waitcnt vmcnt(0)" ::: "memory");
    }
    __builtin_amdgcn_s_barrier();
    __builtin_amdgcn_sched_barrier(0);

    union U8 { intx8 v; uint4 q[2]; };

#define READ_FRAG(dst, base, blk)                                   \
    do {                                                            \
        U8 _u;                                                      \
        const unsigned char* _p = (base) + (blk) * 2048 + lane * 16;\
        _u.q[0] = *(const uint4*)_p;                                \
        _u.q[1] = *(const uint4*)(_p + 1024);                       \
        (dst) = _u.v;                                               \
    } while (0)

#define MFMA8(a0, a1, i0, i1)                                               \
    do {                                                                    \
        __builtin_amdgcn_s_setprio(1);                                      \
        _Pragma("unroll")                                                   \
        for (int j = 0; j < 4; ++j)                                         \
            acc[i0][j] = __builtin_amdgcn_mfma_scale_f32_16x16x128_f8f6f4(  \
                a0, bf[j], acc[i0][j], 0, 0, 0, 0x7F7F7F7F, 0, 0x7F7F7F7F); \
        _Pragma("unroll")                                                   \
        for (int j = 0; j < 4; ++j)                                         \
            acc[i1][j] = __builtin_amdgcn_mfma_scale_f32_16x16x128_f8f6f4(  \
                a1, bf[j], acc[i1][j], 0, 0, 0, 0x7F7F7F7F, 0, 0x7F7F7F7F); \
        __builtin_amdgcn_s_setprio(0);                                      \
    } while (0)

#define PHASE_WAIT()                                             \
    do {                                                         \
        __builtin_amdgcn_s_barrier();                            \
        asm volatile("s_waitcnt lgkmcnt(0)" ::: "memory");       \
        __builtin_amdgcn_sched_barrier(0);                       \
    } while (0)

    for (int kt = 0; kt < NT; ++kt) {
        const unsigned char* Ab = &As[(kt & 1) * 32768];
        const unsigned char* Bb = &Bs[(kt & 1) * 32768];
        unsigned char* An  = &As[((kt + 1) & 1) * 32768];  // A(t+1) target
        unsigned char* Bn2 = &Bs[(kt & 1) * 32768];        // B(t+2) target
        const bool pfA = (kt + 1 < NT);
        const bool pfB = (kt + 2 < NT);

        intx8 bf[4], afa, afb;
        // ---- phase 0: all B frags + A blocks 0,1; DMA A(t+1) units 0,1
        READ_FRAG(bf[0], Bb, wn * 4 + 0);
        READ_FRAG(bf[1], Bb, wn * 4 + 1);
        READ_FRAG(bf[2], Bb, wn * 4 + 2);
        READ_FRAG(bf[3], Bb, wn * 4 + 3);
        READ_FRAG(afa, Ab, wm * 8 + 0);
        READ_FRAG(afb, Ab, wm * 8 + 1);
        if (pfA) {
            gload16(ga[0], An + lo[0]); gload16(ga[1], An + lo[1]);
            ga[0] += 128; ga[1] += 128;
        }
        PHASE_WAIT();
        MFMA8(afa, afb, 0, 1);
        __builtin_amdgcn_s_barrier();

        // ---- phase 1: A blocks 2,3; DMA A(t+1) units 2,3
        READ_FRAG(afa, Ab, wm * 8 + 2);
        READ_FRAG(afb, Ab, wm * 8 + 3);
        if (pfA) {
            gload16(ga[2], An + lo[2]); gload16(ga[3], An + lo[3]);
            ga[2] += 128; ga[3] += 128;
        }
        PHASE_WAIT();
        MFMA8(afa, afb, 2, 3);
        __builtin_amdgcn_s_barrier();

        // ---- phase 2: A blocks 4,5; DMA B(t+2) units 0,1 (B reads done @P0)
        READ_FRAG(afa, Ab, wm * 8 + 4);
        READ_FRAG(afb, Ab, wm * 8 + 5);
        if (pfB) {
            gload16(gb[0], Bn2 + lo[0]); gload16(gb[1], Bn2 + lo[1]);
            gb[0] += 128; gb[1] += 128;
        }
        PHASE_WAIT();
        MFMA8(afa, afb, 4, 5);
        __builtin_amdgcn_s_barrier();

        // ---- phase 3: A blocks 6,7; DMA B(t+2) units 2,3; counted boundary
        READ_FRAG(afa, Ab, wm * 8 + 6);
        READ_FRAG(afb, Ab, wm * 8 + 7);
        if (pfB) {
            gload16(gb[2], Bn2 + lo[2]); gload16(gb[3], Bn2 + lo[3]);
            gb[2] += 128; gb[3] += 128;
        }
        PHASE_WAIT();
        MFMA8(afa, afb, 6, 7);
        if (pfB) {      // steady state: keep newest 4 (B(t+2)) in flight
            asm volatile("s_waitcnt vmcnt(4)" ::: "memory");
        } else {        // tail: everything must land
            asm volatile("s_waitcnt vmcnt(0)" ::: "memory");
        }
        __builtin_amdgcn_s_barrier();
        __builtin_amdgcn_sched_barrier(0);
    }
    (void)M;
#undef READ_FRAG
#undef MFMA8
#undef PHASE_WAIT

    const float scale = iscale[0] * wscale[0];
    const int row0 = bm + wm * 128 + (cq << 2);  // C/D: col=lane&15, row=cq*4+r
    const int col0 = bn + wn * 64 + r16;
#pragma unroll
    for (int j = 0; j < 4; ++j) {
        const int col = col0 + j * 16;
        const float bv = bias[col];
#pragma unroll
        for (int i = 0; i < 8; ++i) {
            const int row = row0 + i * 16;
            float* cp = C + (size_t)row * N + col;
#pragma unroll
            for (int r = 0; r < 4; ++r)
                cp[(size_t)r * N] = acc[i][j][r] * scale + bv;
        }
    }
}

extern "C" void kernel_launch(void* const* d_in, const int* in_sizes, int n_in,
                              void* d_out, int out_size, void* d_ws, size_t ws_size,
                              hipStream_t stream) {
    const float* x          = (const float*)d_in[0];
    const unsigned char* w  = (const unsigned char*)d_in[1];
    const float* wscale     = (const float*)d_in[2];
    const float* iscale     = (const float*)d_in[3];
    const float* bias       = (const float*)d_in[4];
    float* out              = (float*)d_out;

    const int D_OUT = in_sizes[4];            // 8192
    const int D_IN  = in_sizes[1] / D_OUT;    // 2048
    const int M     = in_sizes[0] / D_IN;     // 8192

    int* flag         = (int*)d_ws;
    unsigned char* q  = (unsigned char*)d_ws + 256;
    unsigned char* wt = q + (size_t)M * D_IN;

    detect_kernel<<<1, 256, 0, stream>>>((const unsigned int*)w, flag);
    const int n8 = (M * D_IN) / 8;
    quant_kernel<<<(n8 + 255) / 256, 256, 0, stream>>>(x, (unsigned int*)q, iscale, n8);
    dim3 tg(D_OUT / 64, D_IN / 64);
    ingest_kernel<<<tg, 256, 0, stream>>>(w, wt, flag, D_IN, D_OUT);
    gemm_mxfp8_kernel<<<dim3(D_OUT / 256, M / 256), 512, 0, stream>>>(
        q, wt, out, bias, wscale, iscale, M, D_OUT, D_IN);
}